// Round 7
// baseline (420.468 us; speedup 1.0000x reference)
//
#include <hip/hip_runtime.h>

#define LVAL 2048
#define KNB 30
#define NPOS 66
#define EDGE_IN 416
#define NOUT 128
#define NWF (13 * 8 * 64 * 8)   // 425984 bf16 weight elements (851968 B)
#define NRES (4 * LVAL)         // 8192 residues

typedef __bf16 bf16x8 __attribute__((ext_vector_type(8)));
typedef float f32x4 __attribute__((ext_vector_type(4)));

__device__ __constant__ unsigned char c_PI[24] = {0,2,3,4,1,1,1,1,0,0,0,4,4,3,0,2,3,4,2,3,4,2,3,2};
__device__ __constant__ unsigned char c_PJ[24] = {0,2,3,4,0,2,3,4,2,3,4,2,3,2,1,1,1,1,0,0,0,4,4,3};

// distance exactly as numpy: ((dx*dx)+(dy*dy))+(dz*dz), +1e-6, IEEE sqrt, no FMA contraction
__device__ inline float ca_dist(float ax, float ay, float az, float bx, float by, float bz) {
#pragma clang fp contract(off)
  float dx = bx - ax, dy = by - ay, dz = bz - az;
  float d2 = ((dx * dx) + (dy * dy)) + (dz * dz);
  return sqrtf(d2 + 1e-6f);
}

__device__ inline float wmaxf(float v) {
#pragma unroll
  for (int off = 32; off >= 1; off >>= 1) v = fmaxf(v, __shfl_xor(v, off, 64));
  return v;
}

// find smallest bin with cumulative count >= K over 256 bins (4 bins/lane), intra-wave
__device__ inline unsigned scan_find_bin(const unsigned* hist, int lane, unsigned K) {
  uint4 h = ((const uint4*)hist)[lane];
  unsigned p0 = h.x, p1 = p0 + h.y, p2 = p1 + h.z, p3 = p2 + h.w;
  unsigned v = p3;
#pragma unroll
  for (int off = 1; off < 64; off <<= 1) {
    unsigned o = __shfl_up(v, off, 64);
    if (lane >= off) v += o;
  }
  unsigned excl = v - p3;
  unsigned long long bal = __ballot(v >= K);
  int ff = __builtin_ctzll(bal);
  unsigned bi;
  if (excl + p0 >= K)      bi = 0u;
  else if (excl + p1 >= K) bi = 1u;
  else if (excl + p2 >= K) bi = 2u;
  else                     bi = 3u;
  return (unsigned)__shfl((int)(4u * (unsigned)lane + bi), ff, 64);
}

// prep: (1) pre-swizzle edge_W into bf16 B-fragment order
//       (2) repack (Ca.xyz, mask) -> float4 for coalesced distance loads
//       (3) repack 15 atom floats -> 64B-aligned rows (single cacheline per gather)
__global__ void prep(const float* __restrict__ W, __bf16* __restrict__ wf,
                     const float* __restrict__ X, const float* __restrict__ mask,
                     float4* __restrict__ cm, float* __restrict__ x16) {
  int id = blockIdx.x * 256 + threadIdx.x;
  if (id < NWF) {
    int jj = id & 7, l = (id >> 3) & 63, nt = (id >> 9) & 7, s = id >> 12;
    int k = 32 * s + ((l >> 4) << 3) + jj;
    int n = nt * 16 + (l & 15);
    wf[id] = (__bf16)W[n * EDGE_IN + k];
  } else if (id < NWF + NRES) {
    int cid = id - NWF;
    const float* __restrict__ xr = X + (size_t)cid * 15;
    float4 v; v.x = xr[3]; v.y = xr[4]; v.z = xr[5]; v.w = mask[cid];
    cm[cid] = v;
    float4* __restrict__ o = (float4*)(x16 + (size_t)cid * 16);
    o[0] = make_float4(xr[0], xr[1], xr[2], xr[3]);
    o[1] = make_float4(xr[4], xr[5], xr[6], xr[7]);
    o[2] = make_float4(xr[8], xr[9], xr[10], xr[11]);
    o[3] = make_float4(xr[12], xr[13], xr[14], 0.f);
  }
}

// Per-wave private scratch; strictly sequential lifetimes share one union.
struct __align__(16) FusedWS {
  union {
    unsigned hist[256];           // radix-select histogram        (select)
    unsigned long long list[64];  // compacted survivors           (compact/rank-sort)
    float natoms[452];            // neighbor atoms [k][a][xyz]    (gather -> GEMM)
  } u;                            // 1808 B
  float satoms[16];               // self atoms
  float Dn[32];                   // D_neighbors (sorted, rank k)
  int   nidx[32];                 // neighbor residue index (rank k)
  int   dk[32];                   // positional bucket (rank k)
};                                // 2256 B; x16 waves = 36096 B

// Fused kernel, R3 structure + latency bundle:
//  - 32 rows/block (2 groups of 16, one wave per row): 256 blocks = 1/CU, one
//    generation; B staged ONCE; group-1 select overlaps group-0 GEMM tails.
//  - B staged with NON-TEMPORAL loads: keeps the 106 KB stream out of L1 so
//    cm (32 KB, block-shared) and x16 lines stay L1-resident for select/gather.
//  - gather: one lane per neighbor, 4x float4 row load (was 155 scalar tasks).
//  - RBF recurrence split into even/odd chains (critical path 16 -> ~4 muls);
//    clamp +-16 keeps y^2 finite; zero-behavior beyond |t|>10.2 identical.
__global__ __launch_bounds__(1024, 4)
void pf_fused(const int* __restrict__ ridx, const int* __restrict__ chain,
              const float* __restrict__ posW, const float* __restrict__ posb,
              const float* __restrict__ lng, const float* __restrict__ lnb,
              const __bf16* __restrict__ wf, const float4* __restrict__ cm,
              const float* __restrict__ x16,
              float* __restrict__ outE, float* __restrict__ outI) {
  extern __shared__ char dsm[];                 // 106496 B B-matrix + 16 x FusedWS
  __bf16* ldsB = (__bf16*)dsm;
  FusedWS* wsa = (FusedWS*)(dsm + 106496);

  const int tid = threadIdx.x, lane = tid & 63, wid = tid >> 6;
  FusedWS& w = wsa[wid];
  const int base_row = blockIdx.x * 32;         // 32 rows/block, never crosses a batch
  const int b = base_row >> 11;
  const float4* __restrict__ cmb = cm + (size_t)b * LVAL;
  const float* __restrict__ x16b = x16 + (size_t)(b * LVAL) * 16;

  // ---------------- stage full B into LDS, NON-TEMPORAL (no L1 pollution) ----------------
  {
    const f32x4* __restrict__ wf4 = (const f32x4*)wf;
    f32x4* ldsB4 = (f32x4*)ldsB;
#pragma unroll
    for (int t = 0; t < 7; ++t) {
      int idx = t * 1024 + tid;
      if (idx < 6656) ldsB4[idx] = __builtin_nontemporal_load(&wf4[idx]);
    }
  }

  const int llo = lane & 15, lhi = lane >> 4;
  const bool m1ok = (llo < 14);                 // edge llo+16 < 30 ?

#pragma unroll 1
  for (int g = 0; g < 2; ++g) {
    const int row = base_row + g * 16 + wid;    // one wave per row

    // ---------------- phase 1: distances, one coalesced dwordx4 per candidate ----------------
    float4 me = cm[row];
    const float cax = me.x, cay = me.y, caz = me.z, mi = me.w;

    float Dv[32];
    unsigned mb = 0u;
    float lmax = 0.f;
#pragma unroll
    for (int q = 0; q < 32; ++q) {
      float4 v = cmb[(q << 6) | lane];
      float m2 = mi * v.w;
      float D = m2 * ca_dist(cax, cay, caz, v.x, v.y, v.z);
      Dv[q] = D;
      if (m2 == 0.f) mb |= (1u << q);
      lmax = fmaxf(lmax, D);
    }
    const float Dmax = wmaxf(lmax);
    const float fscb = 255.9f / fmaxf(Dmax, 1e-30f);

    // ---------------- radix select: single level, 256 value-uniform bins ----------------
    { int4 z = {0, 0, 0, 0}; ((int4*)w.u.hist)[lane] = z; }
#pragma unroll
    for (int q = 0; q < 32; ++q) {
      float Dadj = Dv[q] + (((mb >> q) & 1u) ? Dmax : 0.f);
      Dv[q] = Dadj;                                   // Dv now holds D_adjust
      int bin = min((int)(Dadj * fscb), 255);
      atomicAdd(&w.u.hist[bin], 1u);
    }
    const unsigned T1 = scan_find_bin(w.u.hist, lane, 30u);

    // ---------------- compaction (ballot, register-only counter) ----------------
    unsigned cum = 0;
    const unsigned long long lmaskbits = (1ull << lane) - 1ull;
#pragma unroll
    for (int q = 0; q < 32; ++q) {
      int bin = min((int)(Dv[q] * fscb), 255);
      bool pred = ((unsigned)bin <= T1);
      unsigned long long bal = __ballot(pred);
      if (pred) {
        unsigned pos = cum + (unsigned)__popcll(bal & lmaskbits);
        if (pos < 64u) {
          unsigned kb = __float_as_uint(Dv[q]);
          w.u.list[pos] = (((unsigned long long)kb) << 32) | (unsigned)((q << 6) | lane);
        }
      }
      cum += (unsigned)__popcll(bal);
    }
    const unsigned M = min(cum, 64u);

    // ---------------- exact rank-sort of survivors (keys unique via idx bits) ----------------
    unsigned long long mykey = (lane < (int)M) ? w.u.list[lane] : ~0ull;
    unsigned rank = 0;
    for (unsigned s = 0; s < M; ++s) {
      unsigned long long ks = __shfl(mykey, (int)s, 64);
      rank += (ks < mykey) ? 1u : 0u;
    }
    if ((lane < (int)M) && (rank < KNB)) {
      unsigned jj = (unsigned)(mykey & 0xffffffffull);
      w.Dn[rank] = __uint_as_float((unsigned)(mykey >> 32));
      w.nidx[rank] = (int)jj;
      int off = ridx[row] - ridx[b * LVAL + (int)jj];
      int same = (chain[row] == chain[b * LVAL + (int)jj]) ? 1 : 0;
      w.dk[rank] = same ? min(max(off + 32, 0), 64) : 65;
      outI[(size_t)row * KNB + rank] = (float)jj;
    }

    // ---------------- gather: one lane per residue, 4x float4 (64 B row) ----------------
    {
      const float* base = (lane < KNB) ? (x16b + (size_t)((unsigned)w.nidx[lane]) * 16)
                        : (lane == KNB) ? (x16 + (size_t)row * 16) : nullptr;
      if (base) {
        const f32x4 q0 = *(const f32x4*)(base);
        const f32x4 q1 = *(const f32x4*)(base + 4);
        const f32x4 q2 = *(const f32x4*)(base + 8);
        const f32x4 q3 = *(const f32x4*)(base + 12);
        // atoms: N=q0.xyz  Ca=(q0.w,q1.x,q1.y)  C=(q1.z,q1.w,q2.x)  O=q3.xyz
        float nx = q0[0], ny = q0[1], nz = q0[2];
        float ax = q0[3], ay = q1[0], az = q1[1];
        float cx = q1[2], cy = q1[3], cz = q2[0];
        float bvx = ax - nx, bvy = ay - ny, bvz = az - nz;
        float cvx = cx - ax, cvy = cy - ay, cvz = cz - az;
        float avx = bvy * cvz - bvz * cvy;
        float avy = bvz * cvx - bvx * cvz;
        float avz = bvx * cvy - bvy * cvx;
        float cbx = (-0.58273431f * avx + 0.56802827f * bvx) - 0.54067466f * cvx + ax;
        float cby = (-0.58273431f * avy + 0.56802827f * bvy) - 0.54067466f * cvy + ay;
        float cbz = (-0.58273431f * avz + 0.56802827f * bvz) - 0.54067466f * cvz + az;
        float* dst = (lane < KNB) ? &w.u.natoms[lane * 15] : &w.satoms[0];
        dst[0] = nx;  dst[1] = ny;  dst[2] = nz;
        dst[3] = ax;  dst[4] = ay;  dst[5] = az;
        dst[6] = cx;  dst[7] = cy;  dst[8] = cz;
        dst[9] = q3[0]; dst[10] = q3[1]; dst[11] = q3[2];
        dst[12] = cbx; dst[13] = cby; dst[14] = cbz;
      }
    }

    if (g == 0) __syncthreads();   // B staged by all waves (once; group 1 needs no barrier)

    // ---------------- GEMM from LDS-resident B; pair dists computed on the fly ----------------
    f32x4 acc[2][8];
#pragma unroll
    for (int h = 0; h < 2; ++h)
#pragma unroll
      for (int nt = 0; nt < 8; ++nt) { acc[h][nt][0] = 0.f; acc[h][nt][1] = 0.f; acc[h][nt][2] = 0.f; acc[h][nt][3] = 0.f; }

    const bf16x8* __restrict__ Bf = ((const bf16x8*)ldsB) + lane;  // + (s*8+nt)*64

#pragma unroll 1
    for (int s = 0; s < 13; ++s) {
      bf16x8 a0, a1;
      const int f0 = s * 32 + lhi * 8;
      if (f0 < 16) {
        // positional-embedding features f0..f0+7 (only s==0, lhi<2)
        int d0 = w.dk[llo];
        int d1 = m1ok ? w.dk[llo + 16] : 0;
#pragma unroll
        for (int jx = 0; jx < 8; ++jx) {
          int f = f0 + jx;
          float pb = posb[f];
          a0[jx] = (__bf16)(posW[f * NPOS + d0] + pb);
          a1[jx] = m1ok ? (__bf16)(posW[f * NPOS + d1] + pb) : (__bf16)0.f;
        }
      } else {
        const int gi = (f0 - 16) >> 4;            // 0 = rbf0 (Dn), 1..24 = pair gi-1
        const int rbase = (f0 - 16) & 15;         // 0 or 8
        float D0, D1;
        if (gi == 0) {
          D0 = w.Dn[llo];
          D1 = m1ok ? w.Dn[llo + 16] : 2.0f;
        } else {
          int p = gi - 1;
          int i3 = c_PI[p] * 3, j3 = c_PJ[p] * 3;
          float ax = w.satoms[i3], ay = w.satoms[i3 + 1], az = w.satoms[i3 + 2];
          const float* nb0 = &w.u.natoms[llo * 15 + j3];
          D0 = ca_dist(ax, ay, az, nb0[0], nb0[1], nb0[2]);
          if (m1ok) {
            const float* nb1 = &w.u.natoms[(llo + 16) * 15 + j3];
            D1 = ca_dist(ax, ay, az, nb1[0], nb1[1], nb1[2]);
          } else D1 = 2.0f;
        }
        const float mu0 = 2.0f + (4.0f / 3.0f) * (float)rbase;
        // e_j = exp(-(t - j*D)^2), D = 16/15, via EVEN/ODD geometric chains
        // (critical path ~4 muls vs 16). Constants: K1=exp(-2D^2), K3=K1^2,
        // K2=K1^4. Clamp +-16: y^2 = exp(4.2667t-2.2756) <= e^66, finite; for
        // |t|>10.2 exp(-t^2) underflows to 0 -> all-zero, same as before.
        float t0 = fminf(fmaxf((D0 - mu0) * 0.8f, -16.f), 16.f);
        float t1 = fminf(fmaxf((D1 - mu0) * 0.8f, -16.f), 16.f);
        float x0 = __expf(-t0 * t0),            x1 = __expf(-t1 * t1);
        float y0 = __expf(2.1333333f * t0 - 1.1377778f);
        float y1 = __expf(2.1333333f * t1 - 1.1377778f);
        float E0a = x0,        E1a = x1;        // even chain heads (j=0)
        float E0b = x0 * y0,   E1b = x1 * y1;   // odd  chain heads (j=1)
        float C0  = y0 * y0 * 0.10273973f;      // exp(4Dt-4D^2)
        float C1  = y1 * y1 * 0.10273973f;
        float O0  = C0 * 0.0105551f;            // odd-step ratio = C*K3
        float O1  = C1 * 0.0105551f;
        a0[0] = (__bf16)E0a;                 a1[0] = m1ok ? (__bf16)E1a : (__bf16)0.f;
        a0[1] = (__bf16)E0b;                 a1[1] = m1ok ? (__bf16)E1b : (__bf16)0.f;
        E0a *= C0; E1a *= C1; E0b *= O0; E1b *= O1;
        a0[2] = (__bf16)E0a;                 a1[2] = m1ok ? (__bf16)E1a : (__bf16)0.f;
        a0[3] = (__bf16)E0b;                 a1[3] = m1ok ? (__bf16)E1b : (__bf16)0.f;
        C0 *= 1.1141675e-4f; C1 *= 1.1141675e-4f;   // *= K2
        O0 *= 1.1141675e-4f; O1 *= 1.1141675e-4f;
        E0a *= C0; E1a *= C1; E0b *= O0; E1b *= O1;
        a0[4] = (__bf16)E0a;                 a1[4] = m1ok ? (__bf16)E1a : (__bf16)0.f;
        a0[5] = (__bf16)E0b;                 a1[5] = m1ok ? (__bf16)E1b : (__bf16)0.f;
        C0 *= 1.1141675e-4f; C1 *= 1.1141675e-4f;
        O0 *= 1.1141675e-4f; O1 *= 1.1141675e-4f;
        E0a *= C0; E1a *= C1; E0b *= O0; E1b *= O1;
        a0[6] = (__bf16)E0a;                 a1[6] = m1ok ? (__bf16)E1a : (__bf16)0.f;
        a0[7] = (__bf16)E0b;                 a1[7] = m1ok ? (__bf16)E1b : (__bf16)0.f;
      }
      const bf16x8* __restrict__ brow = Bf + s * 512;
      __builtin_amdgcn_s_setprio(1);
#pragma unroll
      for (int nt = 0; nt < 8; ++nt) {
        bf16x8 bb = brow[nt * 64];              // linear ds_read_b128
        acc[0][nt] = __builtin_amdgcn_mfma_f32_16x16x32_bf16(a0, bb, acc[0][nt], 0, 0, 0);
        acc[1][nt] = __builtin_amdgcn_mfma_f32_16x16x32_bf16(a1, bb, acc[1][nt], 0, 0, 0);
      }
      __builtin_amdgcn_s_setprio(0);
    }

    // ---------------- LayerNorm in registers + store ----------------
    float gv[8], bv[8];
#pragma unroll
    for (int nt = 0; nt < 8; ++nt) { gv[nt] = lng[nt * 16 + llo]; bv[nt] = lnb[nt * 16 + llo]; }
    float* __restrict__ oRow = outE + (size_t)row * KNB * NOUT;
#pragma unroll
    for (int h = 0; h < 2; ++h) {
#pragma unroll
      for (int r = 0; r < 4; ++r) {
        float s1 = 0.f;
#pragma unroll
        for (int nt = 0; nt < 8; ++nt) s1 += acc[h][nt][r];
        s1 += __shfl_xor(s1, 1, 64);
        s1 += __shfl_xor(s1, 2, 64);
        s1 += __shfl_xor(s1, 4, 64);
        s1 += __shfl_xor(s1, 8, 64);
        float mu = s1 * (1.0f / 128.0f);
        float s2 = 0.f;
#pragma unroll
        for (int nt = 0; nt < 8; ++nt) { float d = acc[h][nt][r] - mu; s2 += d * d; }
        s2 += __shfl_xor(s2, 1, 64);
        s2 += __shfl_xor(s2, 2, 64);
        s2 += __shfl_xor(s2, 4, 64);
        s2 += __shfl_xor(s2, 8, 64);
        float rstd = rsqrtf(s2 * (1.0f / 128.0f) + 1e-5f);
        int rowm = h * 16 + lhi * 4 + r;
        if (rowm < KNB) {
          float* op = oRow + (size_t)rowm * NOUT + llo;
#pragma unroll
          for (int nt = 0; nt < 8; ++nt)
            op[nt * 16] = (acc[h][nt][r] - mu) * rstd * gv[nt] + bv[nt];
        }
      }
    }
  }
}

extern "C" void kernel_launch(void* const* d_in, const int* in_sizes, int n_in,
                              void* d_out, int out_size, void* d_ws, size_t ws_size,
                              hipStream_t stream) {
  const float* X = (const float*)d_in[0];
  const float* mask = (const float*)d_in[1];
  const int* ridx = (const int*)d_in[2];
  const int* chain = (const int*)d_in[3];
  const float* posW = (const float*)d_in[4];
  const float* posb = (const float*)d_in[5];
  const float* edgeW = (const float*)d_in[6];
  const float* lng = (const float*)d_in[7];
  const float* lnb = (const float*)d_in[8];
  float* outE = (float*)d_out;
  float* outI = outE + (size_t)NRES * KNB * NOUT;

  char* ws = (char*)d_ws;
  __bf16* wf = (__bf16*)ws;                          // 851968 B
  float4* cm = (float4*)(ws + 851968);               // 131072 B  (Ca.xyz, mask)
  float* x16 = (float*)(ws + 851968 + 131072);       // 524288 B  (15 atom floats, 64B rows)
  // workspace footprint: 1507328 B (R3-proven)

  static bool s_attr = false;
  if (!s_attr) {
    (void)hipFuncSetAttribute((const void*)pf_fused,
                              hipFuncAttributeMaxDynamicSharedMemorySize, 147456);
    s_attr = true;
  }
  const int ldsBytes = 106496 + 16 * (int)sizeof(FusedWS);  // 142592

  hipLaunchKernelGGL(prep, dim3((NWF + NRES) / 256), dim3(256), 0, stream,
                     edgeW, wf, X, mask, cm, x16);
  hipLaunchKernelGGL(pf_fused, dim3(NRES / 32), dim3(1024), ldsBytes, stream,
                     ridx, chain, posW, posb, lng, lnb, wf, cm, x16, outE, outI);
}

// Round 8
// 214.902 us; speedup vs baseline: 1.9566x; 1.9566x over previous
//
#include <hip/hip_runtime.h>

#define LVAL 2048
#define KNB 30
#define NPOS 66
#define EDGE_IN 416
#define NOUT 128
#define NWF (13 * 8 * 64 * 8)   // 425984 bf16 weight elements (851968 B)
#define NRES (4 * LVAL)         // 8192 residues

typedef __bf16 bf16x8 __attribute__((ext_vector_type(8)));
typedef float f32x4 __attribute__((ext_vector_type(4)));

__device__ __constant__ unsigned char c_PI[24] = {0,2,3,4,1,1,1,1,0,0,0,4,4,3,0,2,3,4,2,3,4,2,3,2};
__device__ __constant__ unsigned char c_PJ[24] = {0,2,3,4,0,2,3,4,2,3,4,2,3,2,1,1,1,1,0,0,0,4,4,3};

// distance exactly as numpy: ((dx*dx)+(dy*dy))+(dz*dz), +1e-6, IEEE sqrt, no FMA contraction
__device__ inline float ca_dist(float ax, float ay, float az, float bx, float by, float bz) {
#pragma clang fp contract(off)
  float dx = bx - ax, dy = by - ay, dz = bz - az;
  float d2 = ((dx * dx) + (dy * dy)) + (dz * dz);
  return sqrtf(d2 + 1e-6f);
}

__device__ inline float wmaxf(float v) {
#pragma unroll
  for (int off = 32; off >= 1; off >>= 1) v = fmaxf(v, __shfl_xor(v, off, 64));
  return v;
}

// find smallest bin with cumulative count >= K over 256 bins (4 bins/lane), intra-wave
__device__ inline unsigned scan_find_bin(const unsigned* hist, int lane, unsigned K) {
  uint4 h = ((const uint4*)hist)[lane];
  unsigned p0 = h.x, p1 = p0 + h.y, p2 = p1 + h.z, p3 = p2 + h.w;
  unsigned v = p3;
#pragma unroll
  for (int off = 1; off < 64; off <<= 1) {
    unsigned o = __shfl_up(v, off, 64);
    if (lane >= off) v += o;
  }
  unsigned excl = v - p3;
  unsigned long long bal = __ballot(v >= K);
  int ff = __builtin_ctzll(bal);
  unsigned bi;
  if (excl + p0 >= K)      bi = 0u;
  else if (excl + p1 >= K) bi = 1u;
  else if (excl + p2 >= K) bi = 2u;
  else                     bi = 3u;
  return (unsigned)__shfl((int)(4u * (unsigned)lane + bi), ff, 64);
}

// prep: (1) pre-swizzle edge_W into bf16 B-fragment order
//       (2) repack (Ca.xyz, mask) -> float4 for coalesced distance loads
//       (3) repack 15 atom floats -> 64B-aligned rows (single cacheline per gather)
__global__ void prep(const float* __restrict__ W, __bf16* __restrict__ wf,
                     const float* __restrict__ X, const float* __restrict__ mask,
                     float4* __restrict__ cm, float* __restrict__ x16) {
  int id = blockIdx.x * 256 + threadIdx.x;
  if (id < NWF) {
    int jj = id & 7, l = (id >> 3) & 63, nt = (id >> 9) & 7, s = id >> 12;
    int k = 32 * s + ((l >> 4) << 3) + jj;
    int n = nt * 16 + (l & 15);
    wf[id] = (__bf16)W[n * EDGE_IN + k];
  } else if (id < NWF + NRES) {
    int cid = id - NWF;
    const float* __restrict__ xr = X + (size_t)cid * 15;
    float4 v; v.x = xr[3]; v.y = xr[4]; v.z = xr[5]; v.w = mask[cid];
    cm[cid] = v;
    float4* __restrict__ o = (float4*)(x16 + (size_t)cid * 16);
    o[0] = make_float4(xr[0], xr[1], xr[2], xr[3]);
    o[1] = make_float4(xr[4], xr[5], xr[6], xr[7]);
    o[2] = make_float4(xr[8], xr[9], xr[10], xr[11]);
    o[3] = make_float4(xr[12], xr[13], xr[14], 0.f);
  }
}

// Per-wave private scratch; strictly sequential lifetimes share one union.
struct __align__(16) FusedWS {
  union {
    unsigned hist[256];           // radix-select histogram        (select)
    unsigned long long list[64];  // compacted survivors           (compact/rank-sort)
    float natoms[452];            // neighbor atoms [k][a][xyz]    (gather -> GEMM)
  } u;                            // 1808 B
  float satoms[16];               // self atoms
  float Dn[32];                   // D_neighbors (sorted, rank k)
  int   nidx[32];                 // neighbor residue index (rank k)
  int   dk[32];                   // positional bucket (rank k)
};                                // 2256 B; x16 waves = 36096 B

// R3 structure VERBATIM (512 blocks x 16 rows, single pass, plain staging, one
// barrier) -- the proven 107 us schedule. R7's 2-generation loop + NT staging
// caused scratch spills (450 MB writes) and is reverted. Only two local,
// correctness-verified (R7 absmax 0.031) tweaks are kept:
//   (a) gather: one lane per residue, 4x float4 row load, atoms in-register
//   (b) RBF even/odd geometric chains (serial muls 16 -> ~4 per fragment)
__global__ __launch_bounds__(1024, 4)
void pf_fused(const int* __restrict__ ridx, const int* __restrict__ chain,
              const float* __restrict__ posW, const float* __restrict__ posb,
              const float* __restrict__ lng, const float* __restrict__ lnb,
              const __bf16* __restrict__ wf, const float4* __restrict__ cm,
              const float* __restrict__ x16,
              float* __restrict__ outE, float* __restrict__ outI) {
  extern __shared__ char dsm[];                 // 106496 B B-matrix + 16 x FusedWS
  __bf16* ldsB = (__bf16*)dsm;
  FusedWS* wsa = (FusedWS*)(dsm + 106496);

  const int tid = threadIdx.x, lane = tid & 63, wid = tid >> 6;
  FusedWS& w = wsa[wid];
  const int row = blockIdx.x * 16 + wid;        // one wave per row
  const int b = row >> 11;                      // 16-row blocks never cross a batch
  const float4* __restrict__ cmb = cm + (size_t)b * LVAL;

  // ---------------- stage full B into LDS (overlaps with select below) ----------------
  {
    const float4* __restrict__ wf4 = (const float4*)wf;
    float4* ldsB4 = (float4*)ldsB;
#pragma unroll
    for (int t = 0; t < 7; ++t) {
      int idx = t * 1024 + tid;
      if (idx < 6656) ldsB4[idx] = wf4[idx];    // 6656 x 16 B = 106496 B
    }
  }

  // ---------------- phase 1: distances, one coalesced dwordx4 per candidate ----------------
  float4 me = cm[row];
  const float cax = me.x, cay = me.y, caz = me.z, mi = me.w;

  float Dv[32];
  unsigned mb = 0u;
  float lmax = 0.f;
#pragma unroll
  for (int q = 0; q < 32; ++q) {
    float4 v = cmb[(q << 6) | lane];
    float m2 = mi * v.w;
    float D = m2 * ca_dist(cax, cay, caz, v.x, v.y, v.z);
    Dv[q] = D;
    if (m2 == 0.f) mb |= (1u << q);
    lmax = fmaxf(lmax, D);
  }
  const float Dmax = wmaxf(lmax);
  const float fscb = 255.9f / fmaxf(Dmax, 1e-30f);

  // ---------------- radix select: single level, 256 value-uniform bins ----------------
  { int4 z = {0, 0, 0, 0}; ((int4*)w.u.hist)[lane] = z; }
#pragma unroll
  for (int q = 0; q < 32; ++q) {
    float Dadj = Dv[q] + (((mb >> q) & 1u) ? Dmax : 0.f);
    Dv[q] = Dadj;                                     // Dv now holds D_adjust
    int bin = min((int)(Dadj * fscb), 255);
    atomicAdd(&w.u.hist[bin], 1u);
  }
  const unsigned T1 = scan_find_bin(w.u.hist, lane, 30u);

  // ---------------- compaction (ballot, register-only counter); list aliases hist ----------------
  unsigned cum = 0;
  const unsigned long long lmaskbits = (1ull << lane) - 1ull;
#pragma unroll
  for (int q = 0; q < 32; ++q) {
    int bin = min((int)(Dv[q] * fscb), 255);
    bool pred = ((unsigned)bin <= T1);
    unsigned long long bal = __ballot(pred);
    if (pred) {
      unsigned pos = cum + (unsigned)__popcll(bal & lmaskbits);
      if (pos < 64u) {
        unsigned kb = __float_as_uint(Dv[q]);
        w.u.list[pos] = (((unsigned long long)kb) << 32) | (unsigned)((q << 6) | lane);
      }
    }
    cum += (unsigned)__popcll(bal);
  }
  const unsigned M = min(cum, 64u);

  // ---------------- exact rank-sort of survivors (keys unique via idx bits) ----------------
  unsigned long long mykey = (lane < (int)M) ? w.u.list[lane] : ~0ull;
  unsigned rank = 0;
  for (unsigned s = 0; s < M; ++s) {
    unsigned long long ks = __shfl(mykey, (int)s, 64);
    rank += (ks < mykey) ? 1u : 0u;
  }
  if ((lane < (int)M) && (rank < KNB)) {
    unsigned jj = (unsigned)(mykey & 0xffffffffull);
    w.Dn[rank] = __uint_as_float((unsigned)(mykey >> 32));
    w.nidx[rank] = (int)jj;
    int off = ridx[row] - ridx[b * LVAL + (int)jj];
    int same = (chain[row] == chain[b * LVAL + (int)jj]) ? 1 : 0;
    w.dk[rank] = same ? min(max(off + 32, 0), 64) : 65;
    outI[(size_t)row * KNB + rank] = (float)jj;
  }

  // ---------------- gather: one lane per residue, 4x float4 (64 B row) ----------------
  {
    const float* base = (lane < KNB) ? (x16 + ((size_t)(b * LVAL) + (unsigned)w.nidx[lane]) * 16)
                      : (lane == KNB) ? (x16 + (size_t)row * 16) : nullptr;
    if (base) {
      const f32x4 q0 = *(const f32x4*)(base);
      const f32x4 q1 = *(const f32x4*)(base + 4);
      const f32x4 q2 = *(const f32x4*)(base + 8);
      const f32x4 q3 = *(const f32x4*)(base + 12);
      // atoms: N=q0.xyz  Ca=(q0.w,q1.x,q1.y)  C=(q1.z,q1.w,q2.x)  O=q3.xyz
      float nx = q0[0], ny = q0[1], nz = q0[2];
      float ax = q0[3], ay = q1[0], az = q1[1];
      float cx = q1[2], cy = q1[3], cz = q2[0];
      float bvx = ax - nx, bvy = ay - ny, bvz = az - nz;
      float cvx = cx - ax, cvy = cy - ay, cvz = cz - az;
      float avx = bvy * cvz - bvz * cvy;
      float avy = bvz * cvx - bvx * cvz;
      float avz = bvx * cvy - bvy * cvx;
      float cbx = (-0.58273431f * avx + 0.56802827f * bvx) - 0.54067466f * cvx + ax;
      float cby = (-0.58273431f * avy + 0.56802827f * bvy) - 0.54067466f * cvy + ay;
      float cbz = (-0.58273431f * avz + 0.56802827f * bvz) - 0.54067466f * cvz + az;
      float* dst = (lane < KNB) ? &w.u.natoms[lane * 15] : &w.satoms[0];
      dst[0] = nx;  dst[1] = ny;  dst[2] = nz;
      dst[3] = ax;  dst[4] = ay;  dst[5] = az;
      dst[6] = cx;  dst[7] = cy;  dst[8] = cz;
      dst[9] = q3[0]; dst[10] = q3[1]; dst[11] = q3[2];
      dst[12] = cbx; dst[13] = cby; dst[14] = cbz;
    }
  }

  __syncthreads();   // B staged by all waves; also drains the ds_writes above

  // ---------------- GEMM from LDS-resident B; pair dists computed on the fly ----------------
  const int llo = lane & 15, lhi = lane >> 4;
  f32x4 acc[2][8];
#pragma unroll
  for (int h = 0; h < 2; ++h)
#pragma unroll
    for (int nt = 0; nt < 8; ++nt) { acc[h][nt][0] = 0.f; acc[h][nt][1] = 0.f; acc[h][nt][2] = 0.f; acc[h][nt][3] = 0.f; }

  const bf16x8* __restrict__ Bf = ((const bf16x8*)ldsB) + lane;  // + (s*8+nt)*64
  const bool m1ok = (llo < 14);                                   // edge llo+16 < 30 ?

#pragma unroll 1
  for (int s = 0; s < 13; ++s) {
    bf16x8 a0, a1;
    const int f0 = s * 32 + lhi * 8;
    if (f0 < 16) {
      // positional-embedding features f0..f0+7 (only s==0, lhi<2)
      int d0 = w.dk[llo];
      int d1 = m1ok ? w.dk[llo + 16] : 0;
#pragma unroll
      for (int jx = 0; jx < 8; ++jx) {
        int f = f0 + jx;
        float pb = posb[f];
        a0[jx] = (__bf16)(posW[f * NPOS + d0] + pb);
        a1[jx] = m1ok ? (__bf16)(posW[f * NPOS + d1] + pb) : (__bf16)0.f;
      }
    } else {
      const int gi = (f0 - 16) >> 4;            // 0 = rbf0 (Dn), 1..24 = pair gi-1
      const int rbase = (f0 - 16) & 15;         // 0 or 8
      float D0, D1;
      if (gi == 0) {
        D0 = w.Dn[llo];
        D1 = m1ok ? w.Dn[llo + 16] : 2.0f;
      } else {
        int p = gi - 1;
        int i3 = c_PI[p] * 3, j3 = c_PJ[p] * 3;
        float ax = w.satoms[i3], ay = w.satoms[i3 + 1], az = w.satoms[i3 + 2];
        const float* nb0 = &w.u.natoms[llo * 15 + j3];
        D0 = ca_dist(ax, ay, az, nb0[0], nb0[1], nb0[2]);
        if (m1ok) {
          const float* nb1 = &w.u.natoms[(llo + 16) * 15 + j3];
          D1 = ca_dist(ax, ay, az, nb1[0], nb1[1], nb1[2]);
        } else D1 = 2.0f;
      }
      const float mu0 = 2.0f + (4.0f / 3.0f) * (float)rbase;
      // e_j = exp(-(t - j*D)^2), D = 16/15, via EVEN/ODD geometric chains
      // (critical path ~4 muls vs 16). K1=exp(-2D^2)=0.10273973,
      // K3=K1^2=0.0105551, K2=K1^4=1.1141675e-4. Clamp +-16: y^2 <= e^66
      // finite; |t|>10.2 underflows to exact 0 (identical to prior chain).
      float t0 = fminf(fmaxf((D0 - mu0) * 0.8f, -16.f), 16.f);
      float t1 = fminf(fmaxf((D1 - mu0) * 0.8f, -16.f), 16.f);
      float x0 = __expf(-t0 * t0),            x1 = __expf(-t1 * t1);
      float y0 = __expf(2.1333333f * t0 - 1.1377778f);
      float y1 = __expf(2.1333333f * t1 - 1.1377778f);
      float E0a = x0,        E1a = x1;        // even chain heads (j=0)
      float E0b = x0 * y0,   E1b = x1 * y1;   // odd  chain heads (j=1)
      float C0  = y0 * y0 * 0.10273973f;      // even-step ratio exp(4Dt-4D^2)
      float C1  = y1 * y1 * 0.10273973f;
      float O0  = C0 * 0.0105551f;            // odd-step ratio = C*K3
      float O1  = C1 * 0.0105551f;
      a0[0] = (__bf16)E0a;                 a1[0] = m1ok ? (__bf16)E1a : (__bf16)0.f;
      a0[1] = (__bf16)E0b;                 a1[1] = m1ok ? (__bf16)E1b : (__bf16)0.f;
      E0a *= C0; E1a *= C1; E0b *= O0; E1b *= O1;
      a0[2] = (__bf16)E0a;                 a1[2] = m1ok ? (__bf16)E1a : (__bf16)0.f;
      a0[3] = (__bf16)E0b;                 a1[3] = m1ok ? (__bf16)E1b : (__bf16)0.f;
      C0 *= 1.1141675e-4f; C1 *= 1.1141675e-4f;   // *= K2
      O0 *= 1.1141675e-4f; O1 *= 1.1141675e-4f;
      E0a *= C0; E1a *= C1; E0b *= O0; E1b *= O1;
      a0[4] = (__bf16)E0a;                 a1[4] = m1ok ? (__bf16)E1a : (__bf16)0.f;
      a0[5] = (__bf16)E0b;                 a1[5] = m1ok ? (__bf16)E1b : (__bf16)0.f;
      C0 *= 1.1141675e-4f; C1 *= 1.1141675e-4f;
      O0 *= 1.1141675e-4f; O1 *= 1.1141675e-4f;
      E0a *= C0; E1a *= C1; E0b *= O0; E1b *= O1;
      a0[6] = (__bf16)E0a;                 a1[6] = m1ok ? (__bf16)E1a : (__bf16)0.f;
      a0[7] = (__bf16)E0b;                 a1[7] = m1ok ? (__bf16)E1b : (__bf16)0.f;
    }
    const bf16x8* __restrict__ brow = Bf + s * 512;
    __builtin_amdgcn_s_setprio(1);
#pragma unroll
    for (int nt = 0; nt < 8; ++nt) {
      bf16x8 bb = brow[nt * 64];                // linear ds_read_b128
      acc[0][nt] = __builtin_amdgcn_mfma_f32_16x16x32_bf16(a0, bb, acc[0][nt], 0, 0, 0);
      acc[1][nt] = __builtin_amdgcn_mfma_f32_16x16x32_bf16(a1, bb, acc[1][nt], 0, 0, 0);
    }
    __builtin_amdgcn_s_setprio(0);
  }

  // ---------------- LayerNorm in registers + store ----------------
  float gv[8], bv[8];
#pragma unroll
  for (int nt = 0; nt < 8; ++nt) { gv[nt] = lng[nt * 16 + llo]; bv[nt] = lnb[nt * 16 + llo]; }
  float* __restrict__ oRow = outE + (size_t)row * KNB * NOUT;
#pragma unroll
  for (int h = 0; h < 2; ++h) {
#pragma unroll
    for (int r = 0; r < 4; ++r) {
      float s1 = 0.f;
#pragma unroll
      for (int nt = 0; nt < 8; ++nt) s1 += acc[h][nt][r];
      s1 += __shfl_xor(s1, 1, 64);
      s1 += __shfl_xor(s1, 2, 64);
      s1 += __shfl_xor(s1, 4, 64);
      s1 += __shfl_xor(s1, 8, 64);
      float mu = s1 * (1.0f / 128.0f);
      float s2 = 0.f;
#pragma unroll
      for (int nt = 0; nt < 8; ++nt) { float d = acc[h][nt][r] - mu; s2 += d * d; }
      s2 += __shfl_xor(s2, 1, 64);
      s2 += __shfl_xor(s2, 2, 64);
      s2 += __shfl_xor(s2, 4, 64);
      s2 += __shfl_xor(s2, 8, 64);
      float rstd = rsqrtf(s2 * (1.0f / 128.0f) + 1e-5f);
      int rowm = h * 16 + lhi * 4 + r;
      if (rowm < KNB) {
        float* op = oRow + (size_t)rowm * NOUT + llo;
#pragma unroll
        for (int nt = 0; nt < 8; ++nt)
          op[nt * 16] = (acc[h][nt][r] - mu) * rstd * gv[nt] + bv[nt];
      }
    }
  }
}

extern "C" void kernel_launch(void* const* d_in, const int* in_sizes, int n_in,
                              void* d_out, int out_size, void* d_ws, size_t ws_size,
                              hipStream_t stream) {
  const float* X = (const float*)d_in[0];
  const float* mask = (const float*)d_in[1];
  const int* ridx = (const int*)d_in[2];
  const int* chain = (const int*)d_in[3];
  const float* posW = (const float*)d_in[4];
  const float* posb = (const float*)d_in[5];
  const float* edgeW = (const float*)d_in[6];
  const float* lng = (const float*)d_in[7];
  const float* lnb = (const float*)d_in[8];
  float* outE = (float*)d_out;
  float* outI = outE + (size_t)NRES * KNB * NOUT;

  char* ws = (char*)d_ws;
  __bf16* wf = (__bf16*)ws;                          // 851968 B
  float4* cm = (float4*)(ws + 851968);               // 131072 B  (Ca.xyz, mask)
  float* x16 = (float*)(ws + 851968 + 131072);       // 524288 B  (15 atom floats, 64B rows)
  // workspace footprint: 1507328 B (R3-proven)

  static bool s_attr = false;
  if (!s_attr) {
    (void)hipFuncSetAttribute((const void*)pf_fused,
                              hipFuncAttributeMaxDynamicSharedMemorySize, 147456);
    s_attr = true;
  }
  const int ldsBytes = 106496 + 16 * (int)sizeof(FusedWS);  // 142592

  hipLaunchKernelGGL(prep, dim3((NWF + NRES) / 256), dim3(256), 0, stream,
                     edgeW, wf, X, mask, cm, x16);
  hipLaunchKernelGGL(pf_fused, dim3(NRES / 16), dim3(1024), ldsBytes, stream,
                     ridx, chain, posW, posb, lng, lnb, wf, cm, x16, outE, outI);
}

// Round 9
// 214.540 us; speedup vs baseline: 1.9599x; 1.0017x over previous
//
#include <hip/hip_runtime.h>

#define LVAL 2048
#define KNB 30
#define NPOS 66
#define EDGE_IN 416
#define NOUT 128
#define NWF (13 * 8 * 64 * 8)   // 425984 bf16 weight elements (851968 B)
#define NRES (4 * LVAL)         // 8192 residues

typedef __bf16 bf16x8 __attribute__((ext_vector_type(8)));
typedef float f32x4 __attribute__((ext_vector_type(4)));

__device__ __constant__ unsigned char c_PI[24] = {0,2,3,4,1,1,1,1,0,0,0,4,4,3,0,2,3,4,2,3,4,2,3,2};
__device__ __constant__ unsigned char c_PJ[24] = {0,2,3,4,0,2,3,4,2,3,4,2,3,2,1,1,1,1,0,0,0,4,4,3};

// distance exactly as numpy: ((dx*dx)+(dy*dy))+(dz*dz), +1e-6, IEEE sqrt, no FMA contraction
__device__ inline float ca_dist(float ax, float ay, float az, float bx, float by, float bz) {
#pragma clang fp contract(off)
  float dx = bx - ax, dy = by - ay, dz = bz - az;
  float d2 = ((dx * dx) + (dy * dy)) + (dz * dz);
  return sqrtf(d2 + 1e-6f);
}

__device__ inline float wmaxf(float v) {
#pragma unroll
  for (int off = 32; off >= 1; off >>= 1) v = fmaxf(v, __shfl_xor(v, off, 64));
  return v;
}

// find smallest bin with cumulative count >= K over 256 bins (4 bins/lane), intra-wave
__device__ inline unsigned scan_find_bin(const unsigned* hist, int lane, unsigned K) {
  uint4 h = ((const uint4*)hist)[lane];
  unsigned p0 = h.x, p1 = p0 + h.y, p2 = p1 + h.z, p3 = p2 + h.w;
  unsigned v = p3;
#pragma unroll
  for (int off = 1; off < 64; off <<= 1) {
    unsigned o = __shfl_up(v, off, 64);
    if (lane >= off) v += o;
  }
  unsigned excl = v - p3;
  unsigned long long bal = __ballot(v >= K);
  int ff = __builtin_ctzll(bal);
  unsigned bi;
  if (excl + p0 >= K)      bi = 0u;
  else if (excl + p1 >= K) bi = 1u;
  else if (excl + p2 >= K) bi = 2u;
  else                     bi = 3u;
  return (unsigned)__shfl((int)(4u * (unsigned)lane + bi), ff, 64);
}

// prep: (1) pre-swizzle edge_W into bf16 B-fragment order
//       (2) repack (Ca.xyz, mask) -> float4 for coalesced distance loads
//       (3) repack 15 atom floats -> 64B-aligned rows (single cacheline per gather)
__global__ void prep(const float* __restrict__ W, __bf16* __restrict__ wf,
                     const float* __restrict__ X, const float* __restrict__ mask,
                     float4* __restrict__ cm, float* __restrict__ x16) {
  int id = blockIdx.x * 256 + threadIdx.x;
  if (id < NWF) {
    int jj = id & 7, l = (id >> 3) & 63, nt = (id >> 9) & 7, s = id >> 12;
    int k = 32 * s + ((l >> 4) << 3) + jj;
    int n = nt * 16 + (l & 15);
    wf[id] = (__bf16)W[n * EDGE_IN + k];
  } else if (id < NWF + NRES) {
    int cid = id - NWF;
    const float* __restrict__ xr = X + (size_t)cid * 15;
    float4 v; v.x = xr[3]; v.y = xr[4]; v.z = xr[5]; v.w = mask[cid];
    cm[cid] = v;
    float4* __restrict__ o = (float4*)(x16 + (size_t)cid * 16);
    o[0] = make_float4(xr[0], xr[1], xr[2], xr[3]);
    o[1] = make_float4(xr[4], xr[5], xr[6], xr[7]);
    o[2] = make_float4(xr[8], xr[9], xr[10], xr[11]);
    o[3] = make_float4(xr[12], xr[13], xr[14], 0.f);
  }
}

// Per-wave private scratch; strictly sequential lifetimes share one union.
struct __align__(16) FusedWS {
  union {
    unsigned hist[256];           // radix-select histogram        (select)
    unsigned long long list[64];  // compacted survivors           (compact/rank-sort)
    float natoms[452];            // neighbor atoms [k][a][xyz]    (gather -> GEMM)
  } u;                            // 1808 B
  float satoms[16];               // self atoms
  float Dn[32];                   // D_neighbors (sorted, rank k)
  int   nidx[32];                 // neighbor residue index (rank k)
  int   dk[32];                   // positional bucket (rank k)
};                                // 2256 B; x16 waves = 36096 B

// R8 structure (proven 103 us) + two register-neutral micro-opts:
//   (a) B staged with NON-TEMPORAL loads (isolated this time): keeps the 106 KB
//       weight stream out of L1 so the block-shared 32 KB cm region and x16
//       lines stay L1-resident for the select/gather loads (32/lane).
//   (b) rank-sort reads survivor keys via uniform-address LDS broadcast
//       (1 ds_read_b64/iter) instead of 64-bit __shfl (2 ds_bpermute/iter).
// Rejected (measured or arithmetic): cached-bin packing (+8 VGPR crosses the
// 128-reg occupancy cliff), fp8 B (precision risk, no occupancy gain), 32x32
// MFMA reshape (small upside, layout risk), earlier barrier (loses staging-
// latency hiding under select).
__global__ __launch_bounds__(1024, 4)
void pf_fused(const int* __restrict__ ridx, const int* __restrict__ chain,
              const float* __restrict__ posW, const float* __restrict__ posb,
              const float* __restrict__ lng, const float* __restrict__ lnb,
              const __bf16* __restrict__ wf, const float4* __restrict__ cm,
              const float* __restrict__ x16,
              float* __restrict__ outE, float* __restrict__ outI) {
  extern __shared__ char dsm[];                 // 106496 B B-matrix + 16 x FusedWS
  __bf16* ldsB = (__bf16*)dsm;
  FusedWS* wsa = (FusedWS*)(dsm + 106496);

  const int tid = threadIdx.x, lane = tid & 63, wid = tid >> 6;
  FusedWS& w = wsa[wid];
  const int row = blockIdx.x * 16 + wid;        // one wave per row
  const int b = row >> 11;                      // 16-row blocks never cross a batch
  const float4* __restrict__ cmb = cm + (size_t)b * LVAL;

  // ---------------- stage full B into LDS, NON-TEMPORAL (no L1 pollution) ----------------
  {
    const f32x4* __restrict__ wf4 = (const f32x4*)wf;
    f32x4* ldsB4 = (f32x4*)ldsB;
#pragma unroll
    for (int t = 0; t < 7; ++t) {
      int idx = t * 1024 + tid;
      if (idx < 6656) ldsB4[idx] = __builtin_nontemporal_load(&wf4[idx]);
    }
  }

  // ---------------- phase 1: distances, one coalesced dwordx4 per candidate ----------------
  float4 me = cm[row];
  const float cax = me.x, cay = me.y, caz = me.z, mi = me.w;

  float Dv[32];
  unsigned mb = 0u;
  float lmax = 0.f;
#pragma unroll
  for (int q = 0; q < 32; ++q) {
    float4 v = cmb[(q << 6) | lane];
    float m2 = mi * v.w;
    float D = m2 * ca_dist(cax, cay, caz, v.x, v.y, v.z);
    Dv[q] = D;
    if (m2 == 0.f) mb |= (1u << q);
    lmax = fmaxf(lmax, D);
  }
  const float Dmax = wmaxf(lmax);
  const float fscb = 255.9f / fmaxf(Dmax, 1e-30f);

  // ---------------- radix select: single level, 256 value-uniform bins ----------------
  { int4 z = {0, 0, 0, 0}; ((int4*)w.u.hist)[lane] = z; }
#pragma unroll
  for (int q = 0; q < 32; ++q) {
    float Dadj = Dv[q] + (((mb >> q) & 1u) ? Dmax : 0.f);
    Dv[q] = Dadj;                                     // Dv now holds D_adjust
    int bin = min((int)(Dadj * fscb), 255);
    atomicAdd(&w.u.hist[bin], 1u);
  }
  const unsigned T1 = scan_find_bin(w.u.hist, lane, 30u);

  // ---------------- compaction (ballot, register-only counter); list aliases hist ----------------
  unsigned cum = 0;
  const unsigned long long lmaskbits = (1ull << lane) - 1ull;
#pragma unroll
  for (int q = 0; q < 32; ++q) {
    int bin = min((int)(Dv[q] * fscb), 255);
    bool pred = ((unsigned)bin <= T1);
    unsigned long long bal = __ballot(pred);
    if (pred) {
      unsigned pos = cum + (unsigned)__popcll(bal & lmaskbits);
      if (pos < 64u) {
        unsigned kb = __float_as_uint(Dv[q]);
        w.u.list[pos] = (((unsigned long long)kb) << 32) | (unsigned)((q << 6) | lane);
      }
    }
    cum += (unsigned)__popcll(bal);
  }
  const unsigned M = min(cum, 64u);

  // ---------------- exact rank-sort of survivors (keys unique via idx bits) ----------------
  // keys are in wave-private LDS; uniform-address broadcast read (1 ds_read_b64)
  // replaces 64-bit __shfl (2 ds_bpermute) per iteration. Same wave wrote the
  // list above, so in-wave LDS ordering guarantees visibility (no barrier).
  unsigned long long mykey = (lane < (int)M) ? w.u.list[lane] : ~0ull;
  unsigned rank = 0;
  for (unsigned s = 0; s < M; ++s) {
    unsigned long long ks = w.u.list[s];
    rank += (ks < mykey) ? 1u : 0u;
  }
  if ((lane < (int)M) && (rank < KNB)) {
    unsigned jj = (unsigned)(mykey & 0xffffffffull);
    w.Dn[rank] = __uint_as_float((unsigned)(mykey >> 32));
    w.nidx[rank] = (int)jj;
    int off = ridx[row] - ridx[b * LVAL + (int)jj];
    int same = (chain[row] == chain[b * LVAL + (int)jj]) ? 1 : 0;
    w.dk[rank] = same ? min(max(off + 32, 0), 64) : 65;
    outI[(size_t)row * KNB + rank] = (float)jj;
  }

  // ---------------- gather: one lane per residue, 4x float4 (64 B row) ----------------
  {
    const float* base = (lane < KNB) ? (x16 + ((size_t)(b * LVAL) + (unsigned)w.nidx[lane]) * 16)
                      : (lane == KNB) ? (x16 + (size_t)row * 16) : nullptr;
    if (base) {
      const f32x4 q0 = *(const f32x4*)(base);
      const f32x4 q1 = *(const f32x4*)(base + 4);
      const f32x4 q2 = *(const f32x4*)(base + 8);
      const f32x4 q3 = *(const f32x4*)(base + 12);
      // atoms: N=q0.xyz  Ca=(q0.w,q1.x,q1.y)  C=(q1.z,q1.w,q2.x)  O=q3.xyz
      float nx = q0[0], ny = q0[1], nz = q0[2];
      float ax = q0[3], ay = q1[0], az = q1[1];
      float cx = q1[2], cy = q1[3], cz = q2[0];
      float bvx = ax - nx, bvy = ay - ny, bvz = az - nz;
      float cvx = cx - ax, cvy = cy - ay, cvz = cz - az;
      float avx = bvy * cvz - bvz * cvy;
      float avy = bvz * cvx - bvx * cvz;
      float avz = bvx * cvy - bvy * cvx;
      float cbx = (-0.58273431f * avx + 0.56802827f * bvx) - 0.54067466f * cvx + ax;
      float cby = (-0.58273431f * avy + 0.56802827f * bvy) - 0.54067466f * cvy + ay;
      float cbz = (-0.58273431f * avz + 0.56802827f * bvz) - 0.54067466f * cvz + az;
      float* dst = (lane < KNB) ? &w.u.natoms[lane * 15] : &w.satoms[0];
      dst[0] = nx;  dst[1] = ny;  dst[2] = nz;
      dst[3] = ax;  dst[4] = ay;  dst[5] = az;
      dst[6] = cx;  dst[7] = cy;  dst[8] = cz;
      dst[9] = q3[0]; dst[10] = q3[1]; dst[11] = q3[2];
      dst[12] = cbx; dst[13] = cby; dst[14] = cbz;
    }
  }

  __syncthreads();   // B staged by all waves; also drains the ds_writes above

  // ---------------- GEMM from LDS-resident B; pair dists computed on the fly ----------------
  const int llo = lane & 15, lhi = lane >> 4;
  f32x4 acc[2][8];
#pragma unroll
  for (int h = 0; h < 2; ++h)
#pragma unroll
    for (int nt = 0; nt < 8; ++nt) { acc[h][nt][0] = 0.f; acc[h][nt][1] = 0.f; acc[h][nt][2] = 0.f; acc[h][nt][3] = 0.f; }

  const bf16x8* __restrict__ Bf = ((const bf16x8*)ldsB) + lane;  // + (s*8+nt)*64
  const bool m1ok = (llo < 14);                                   // edge llo+16 < 30 ?

#pragma unroll 1
  for (int s = 0; s < 13; ++s) {
    bf16x8 a0, a1;
    const int f0 = s * 32 + lhi * 8;
    if (f0 < 16) {
      // positional-embedding features f0..f0+7 (only s==0, lhi<2)
      int d0 = w.dk[llo];
      int d1 = m1ok ? w.dk[llo + 16] : 0;
#pragma unroll
      for (int jx = 0; jx < 8; ++jx) {
        int f = f0 + jx;
        float pb = posb[f];
        a0[jx] = (__bf16)(posW[f * NPOS + d0] + pb);
        a1[jx] = m1ok ? (__bf16)(posW[f * NPOS + d1] + pb) : (__bf16)0.f;
      }
    } else {
      const int gi = (f0 - 16) >> 4;            // 0 = rbf0 (Dn), 1..24 = pair gi-1
      const int rbase = (f0 - 16) & 15;         // 0 or 8
      float D0, D1;
      if (gi == 0) {
        D0 = w.Dn[llo];
        D1 = m1ok ? w.Dn[llo + 16] : 2.0f;
      } else {
        int p = gi - 1;
        int i3 = c_PI[p] * 3, j3 = c_PJ[p] * 3;
        float ax = w.satoms[i3], ay = w.satoms[i3 + 1], az = w.satoms[i3 + 2];
        const float* nb0 = &w.u.natoms[llo * 15 + j3];
        D0 = ca_dist(ax, ay, az, nb0[0], nb0[1], nb0[2]);
        if (m1ok) {
          const float* nb1 = &w.u.natoms[(llo + 16) * 15 + j3];
          D1 = ca_dist(ax, ay, az, nb1[0], nb1[1], nb1[2]);
        } else D1 = 2.0f;
      }
      const float mu0 = 2.0f + (4.0f / 3.0f) * (float)rbase;
      // e_j = exp(-(t - j*D)^2), D = 16/15, via EVEN/ODD geometric chains
      // (critical path ~4 muls vs 16). K1=exp(-2D^2)=0.10273973,
      // K3=K1^2=0.0105551, K2=K1^4=1.1141675e-4. Clamp +-16: y^2 <= e^66
      // finite; |t|>10.2 underflows to exact 0 (identical to prior chain).
      float t0 = fminf(fmaxf((D0 - mu0) * 0.8f, -16.f), 16.f);
      float t1 = fminf(fmaxf((D1 - mu0) * 0.8f, -16.f), 16.f);
      float x0 = __expf(-t0 * t0),            x1 = __expf(-t1 * t1);
      float y0 = __expf(2.1333333f * t0 - 1.1377778f);
      float y1 = __expf(2.1333333f * t1 - 1.1377778f);
      float E0a = x0,        E1a = x1;        // even chain heads (j=0)
      float E0b = x0 * y0,   E1b = x1 * y1;   // odd  chain heads (j=1)
      float C0  = y0 * y0 * 0.10273973f;      // even-step ratio exp(4Dt-4D^2)
      float C1  = y1 * y1 * 0.10273973f;
      float O0  = C0 * 0.0105551f;            // odd-step ratio = C*K3
      float O1  = C1 * 0.0105551f;
      a0[0] = (__bf16)E0a;                 a1[0] = m1ok ? (__bf16)E1a : (__bf16)0.f;
      a0[1] = (__bf16)E0b;                 a1[1] = m1ok ? (__bf16)E1b : (__bf16)0.f;
      E0a *= C0; E1a *= C1; E0b *= O0; E1b *= O1;
      a0[2] = (__bf16)E0a;                 a1[2] = m1ok ? (__bf16)E1a : (__bf16)0.f;
      a0[3] = (__bf16)E0b;                 a1[3] = m1ok ? (__bf16)E1b : (__bf16)0.f;
      C0 *= 1.1141675e-4f; C1 *= 1.1141675e-4f;   // *= K2
      O0 *= 1.1141675e-4f; O1 *= 1.1141675e-4f;
      E0a *= C0; E1a *= C1; E0b *= O0; E1b *= O1;
      a0[4] = (__bf16)E0a;                 a1[4] = m1ok ? (__bf16)E1a : (__bf16)0.f;
      a0[5] = (__bf16)E0b;                 a1[5] = m1ok ? (__bf16)E1b : (__bf16)0.f;
      C0 *= 1.1141675e-4f; C1 *= 1.1141675e-4f;
      O0 *= 1.1141675e-4f; O1 *= 1.1141675e-4f;
      E0a *= C0; E1a *= C1; E0b *= O0; E1b *= O1;
      a0[6] = (__bf16)E0a;                 a1[6] = m1ok ? (__bf16)E1a : (__bf16)0.f;
      a0[7] = (__bf16)E0b;                 a1[7] = m1ok ? (__bf16)E1b : (__bf16)0.f;
    }
    const bf16x8* __restrict__ brow = Bf + s * 512;
    __builtin_amdgcn_s_setprio(1);
#pragma unroll
    for (int nt = 0; nt < 8; ++nt) {
      bf16x8 bb = brow[nt * 64];                // linear ds_read_b128
      acc[0][nt] = __builtin_amdgcn_mfma_f32_16x16x32_bf16(a0, bb, acc[0][nt], 0, 0, 0);
      acc[1][nt] = __builtin_amdgcn_mfma_f32_16x16x32_bf16(a1, bb, acc[1][nt], 0, 0, 0);
    }
    __builtin_amdgcn_s_setprio(0);
  }

  // ---------------- LayerNorm in registers + store ----------------
  float gv[8], bv[8];
#pragma unroll
  for (int nt = 0; nt < 8; ++nt) { gv[nt] = lng[nt * 16 + llo]; bv[nt] = lnb[nt * 16 + llo]; }
  float* __restrict__ oRow = outE + (size_t)row * KNB * NOUT;
#pragma unroll
  for (int h = 0; h < 2; ++h) {
#pragma unroll
    for (int r = 0; r < 4; ++r) {
      float s1 = 0.f;
#pragma unroll
      for (int nt = 0; nt < 8; ++nt) s1 += acc[h][nt][r];
      s1 += __shfl_xor(s1, 1, 64);
      s1 += __shfl_xor(s1, 2, 64);
      s1 += __shfl_xor(s1, 4, 64);
      s1 += __shfl_xor(s1, 8, 64);
      float mu = s1 * (1.0f / 128.0f);
      float s2 = 0.f;
#pragma unroll
      for (int nt = 0; nt < 8; ++nt) { float d = acc[h][nt][r] - mu; s2 += d * d; }
      s2 += __shfl_xor(s2, 1, 64);
      s2 += __shfl_xor(s2, 2, 64);
      s2 += __shfl_xor(s2, 4, 64);
      s2 += __shfl_xor(s2, 8, 64);
      float rstd = rsqrtf(s2 * (1.0f / 128.0f) + 1e-5f);
      int rowm = h * 16 + lhi * 4 + r;
      if (rowm < KNB) {
        float* op = oRow + (size_t)rowm * NOUT + llo;
#pragma unroll
        for (int nt = 0; nt < 8; ++nt)
          op[nt * 16] = (acc[h][nt][r] - mu) * rstd * gv[nt] + bv[nt];
      }
    }
  }
}

extern "C" void kernel_launch(void* const* d_in, const int* in_sizes, int n_in,
                              void* d_out, int out_size, void* d_ws, size_t ws_size,
                              hipStream_t stream) {
  const float* X = (const float*)d_in[0];
  const float* mask = (const float*)d_in[1];
  const int* ridx = (const int*)d_in[2];
  const int* chain = (const int*)d_in[3];
  const float* posW = (const float*)d_in[4];
  const float* posb = (const float*)d_in[5];
  const float* edgeW = (const float*)d_in[6];
  const float* lng = (const float*)d_in[7];
  const float* lnb = (const float*)d_in[8];
  float* outE = (float*)d_out;
  float* outI = outE + (size_t)NRES * KNB * NOUT;

  char* ws = (char*)d_ws;
  __bf16* wf = (__bf16*)ws;                          // 851968 B
  float4* cm = (float4*)(ws + 851968);               // 131072 B  (Ca.xyz, mask)
  float* x16 = (float*)(ws + 851968 + 131072);       // 524288 B  (15 atom floats, 64B rows)
  // workspace footprint: 1507328 B (R3-proven)

  static bool s_attr = false;
  if (!s_attr) {
    (void)hipFuncSetAttribute((const void*)pf_fused,
                              hipFuncAttributeMaxDynamicSharedMemorySize, 147456);
    s_attr = true;
  }
  const int ldsBytes = 106496 + 16 * (int)sizeof(FusedWS);  // 142592

  hipLaunchKernelGGL(prep, dim3((NWF + NRES) / 256), dim3(256), 0, stream,
                     edgeW, wf, X, mask, cm, x16);
  hipLaunchKernelGGL(pf_fused, dim3(NRES / 16), dim3(1024), ldsBytes, stream,
                     ridx, chain, posW, posb, lng, lnb, wf, cm, x16, outE, outI);
}